// Round 1
// baseline (312.390 us; speedup 1.0000x reference)
//
#include <hip/hip_runtime.h>
#include <stdint.h>

#define NB   16
#define CD   256
#define HW   1024
#define NQ   16384
#define KCN  8192

typedef unsigned long long u64;
typedef unsigned short     u16;
using f32x4  = __attribute__((ext_vector_type(4))) float;
using bf16x8 = __attribute__((ext_vector_type(8))) __bf16;

// ---------------- workspace layout (~16.9 MB) ----------------
#define ZTB_OFF  0            // u16  [NQ][CD]    8 MB  (z transposed, bf16)
#define EMBB_OFF 8388608      // u16  [KCN][CD]   4 MB  (emb, bf16)
#define EH_OFF   12582912     // f32  [KCN]      32 KB  (||e||^2/2 + 1024)
#define CAND_OFF 12615680     // u64  [NQ][32]    4 MB  (8 splits x 2 halves x top-2)

static __device__ __forceinline__ void gl_lds16(const void* g, void* l) {
  __builtin_amdgcn_global_load_lds(
      (const __attribute__((address_space(1))) void*)g,
      (__attribute__((address_space(3))) void*)l, 16, 0, 0);
}

static __device__ __forceinline__ unsigned bf16r(float x) {  // RNE fp32->bf16 bits
  unsigned u = __float_as_uint(x);
  return (u + 0x7fffu + ((u >> 16) & 1u)) >> 16;
}

static __device__ __forceinline__ u64 umin64(u64 a, u64 b) { return a < b ? a : b; }
static __device__ __forceinline__ u64 umax64(u64 a, u64 b) { return a < b ? b : a; }

// ---------------- kernel 1: merged prep ----------------
__global__ __launch_bounds__(256) void k_prep(const float* __restrict__ z,
                                              const float* __restrict__ emb,
                                              u16* __restrict__ zTb,
                                              u16* __restrict__ embB,
                                              float* __restrict__ eH) {
  const int bx = (int)blockIdx.x;
  if (bx < 1024) {
    __shared__ float tile[64][65];
    const int b   = bx >> 6;
    const int hwT = (bx >> 2) & 15;
    const int cT  = bx & 3;
    const int tx  = threadIdx.x & 63;
    const int ty  = threadIdx.x >> 6;
    const float* src = z + (size_t)(b * CD + cT * 64) * HW + hwT * 64;
#pragma unroll
    for (int i = 0; i < 16; ++i) {
      const int c_l = ty + 4 * i;
      tile[c_l][tx] = src[(size_t)c_l * HW + tx];
    }
    __syncthreads();
    const size_t dbase = (size_t)(b * HW + hwT * 64) * CD + cT * 64;
#pragma unroll
    for (int i = 0; i < 16; ++i) {
      const int hw_l = ty + 4 * i;
      zTb[dbase + (size_t)hw_l * CD + tx] = (u16)bf16r(tile[tx][hw_l]);
    }
  } else {
    const int wave = (bx - 1024) * 4 + ((int)threadIdx.x >> 6);  // 0..1023
    const int lane = threadIdx.x & 63;
#pragma unroll
    for (int it = 0; it < 8; ++it) {
      const int row = wave * 8 + it;
      const float4 v = *(const float4*)(emb + (size_t)row * CD + lane * 4);
      uint2 pk;
      pk.x = bf16r(v.x) | (bf16r(v.y) << 16);
      pk.y = bf16r(v.z) | (bf16r(v.w) << 16);
      *(uint2*)(embB + (size_t)row * CD + lane * 4) = pk;
      float s = v.x * v.x + v.y * v.y + v.z * v.z + v.w * v.w;
#pragma unroll
      for (int off = 32; off; off >>= 1) s += __shfl_xor(s, off, 64);
      if (lane == 0) eH[row] = 0.5f * s + 1024.0f;
    }
  }
}

// ---------------- kernel 2: MFMA GEMM + fused top-2 argmin (R10: BK=32, 4 blocks/CU) ----
// R9 sat at 64KB LDS -> 2 blocks/CU (the m132 occupancy regression): MfmaUtil 29%.
// R10: BK=32 double-buffer -> 4 x 8KB = 32KB LDS; with VGPR<=128 (__launch_bounds 256,4)
// -> 4 blocks/CU, grid 1024 fully co-resident. Per interval: 4 gl_lds16 prefetch,
// 8 ds_read_b128, 16 MFMA, 1 barrier. Staging bases fixed; kc offsets are compile-time
// immediates. LDS rows are 64B (32 bf16); XOR swizzle granule = slot ^ ((row>>1)&3)
// keeps each 16-lane b128 read phase at 2-way bank aliasing (free). Epilogue unchanged.
#define NT  8

__global__ __launch_bounds__(256, 4) void k_argmin(const u16* __restrict__ zTb,
                                                   const u16* __restrict__ embB,
                                                   const float* __restrict__ eH,
                                                   u64* __restrict__ cand) {
  __shared__ __align__(16) u16 As0[128 * 32];   // 8 KB each
  __shared__ __align__(16) u16 Bs0[128 * 32];
  __shared__ __align__(16) u16 As1[128 * 32];
  __shared__ __align__(16) u16 Bs1[128 * 32];
  const int tid  = threadIdx.x;
  const int w    = tid >> 6;
  const int lane = tid & 63;
  const int l15  = lane & 15, quad = lane >> 4;
  const int q0    = (int)(blockIdx.x >> 3) * 128;
  const int split = (int)(blockIdx.x & 7);
  const int wq0 = (w & 1) * 64, wn0 = (w >> 1) * 64, wh = w >> 1;

  // staging: thread t covers rows (t>>2) and (t>>2)+64 of the 128-row tile,
  // LDS 16B slot (t&3); source granule XOR-swizzled: g0 = (t&3) ^ ((row>>1)&3)
  // (identical for row and row+64 since 64>>1 = 32 == 0 mod 4).
  const int srow = tid >> 2;                       // 0..63
  const int g0   = (tid & 3) ^ ((srow >> 1) & 3);
  const int ldsD0 = tid * 16;                      // rows 0..63   (linear dest)
  const int ldsD1 = 4096 + tid * 16;               // rows 64..127
  const char* aSrcT = (const char*)(zTb + (size_t)(q0 + srow) * CD) + g0 * 16;
  const char* bSrcT = (const char*)(embB + (size_t)(split * 1024 + srow) * CD) + g0 * 16;

  // frag reads: lane (quad,l15) wants k-granule=quad of row; stored at slot
  // quad ^ ((row>>1)&3) = quad ^ ((l15>>1)&3)  (row = wq0 + i*16 + l15).
  const int co  = (quad ^ ((l15 >> 1) & 3)) * 16;
  const int aRd = (wq0 + l15) * 64 + co;           // + i*1024 per 16-row tile
  const int bRd = (wn0 + l15) * 64 + co;

  const float FMAX = __uint_as_float(0x7F7FFFFFu);
  float b1[16], b2[16];
#pragma unroll
  for (int s = 0; s < 16; ++s) { b1[s] = FMAX; b2[s] = FMAX; }

  f32x4 acc[4][4];

  // prologue: stage chunk kc=0 of nt=0 into buffer 0
  gl_lds16(aSrcT,         (char*)As0 + ldsD0);
  gl_lds16(aSrcT + 32768, (char*)As0 + ldsD1);     // +64 rows * 512B
  gl_lds16(bSrcT,         (char*)Bs0 + ldsD0);
  gl_lds16(bSrcT + 32768, (char*)Bs0 + ldsD1);
  __syncthreads();

// one K-interval (BK=32): prefetch next chunk into idle buffer, 16 MFMA, 1 barrier
#define KSTEP(PA, PB, NA, NB, AP, BP)                                                \
  do {                                                                               \
    gl_lds16((AP),         (char*)(NA) + ldsD0);                                     \
    gl_lds16((AP) + 32768, (char*)(NA) + ldsD1);                                     \
    gl_lds16((BP),         (char*)(NB) + ldsD0);                                     \
    gl_lds16((BP) + 32768, (char*)(NB) + ldsD1);                                     \
    bf16x8 af[4], bfr[4];                                                            \
    _Pragma("unroll")                                                                \
    for (int i = 0; i < 4; ++i)                                                      \
      af[i] = *(const bf16x8*)((const char*)(PA) + aRd + i * 1024);                  \
    _Pragma("unroll")                                                                \
    for (int j = 0; j < 4; ++j)                                                      \
      bfr[j] = *(const bf16x8*)((const char*)(PB) + bRd + j * 1024);                 \
    _Pragma("unroll")                                                                \
    for (int i = 0; i < 4; ++i)                                                      \
      _Pragma("unroll")                                                              \
      for (int j = 0; j < 4; ++j)                                                    \
        acc[i][j] = __builtin_amdgcn_mfma_f32_16x16x32_bf16(af[i], bfr[j],           \
                                                            acc[i][j], 0, 0, 0);     \
    __syncthreads();                                                                 \
  } while (0)

  for (int nt = 0; nt < NT; ++nt) {
    const int n0 = split * 1024 + nt * 128;
    const char* bNext = (nt == NT - 1) ? bSrcT : (bSrcT + 65536);  // last: dummy restage
    float eh[4];
#pragma unroll
    for (int j = 0; j < 4; ++j) eh[j] = eH[n0 + wn0 + 16 * j + l15];

#pragma unroll
    for (int i = 0; i < 4; ++i)
#pragma unroll
      for (int j = 0; j < 4; ++j) acc[i][j] = f32x4{0.f, 0.f, 0.f, 0.f};

    KSTEP(As0, Bs0, As1, Bs1, aSrcT + 64,  bSrcT + 64);    // kc=0, prefetch 1
    KSTEP(As1, Bs1, As0, Bs0, aSrcT + 128, bSrcT + 128);   // kc=1, prefetch 2
    KSTEP(As0, Bs0, As1, Bs1, aSrcT + 192, bSrcT + 192);   // kc=2, prefetch 3
    KSTEP(As1, Bs1, As0, Bs0, aSrcT + 256, bSrcT + 256);   // kc=3, prefetch 4
    KSTEP(As0, Bs0, As1, Bs1, aSrcT + 320, bSrcT + 320);   // kc=4, prefetch 5
    KSTEP(As1, Bs1, As0, Bs0, aSrcT + 384, bSrcT + 384);   // kc=5, prefetch 6
    KSTEP(As0, Bs0, As1, Bs1, aSrcT + 448, bSrcT + 448);   // kc=6, prefetch 7
    KSTEP(As1, Bs1, As0, Bs0, aSrcT + 0,   bNext);         // kc=7, prefetch next nt kc=0

    // ---- fp32 epilogue: key = (||e||^2/2+1024) - z.e, quantized, id=(nt*4+j) in low 5 bits
#pragma unroll
    for (int i = 0; i < 4; ++i) {
#pragma unroll
      for (int r = 0; r < 4; ++r) {
        const int s = i * 4 + r;
        float kq[4];
#pragma unroll
        for (int j = 0; j < 4; ++j) {
          const unsigned kb = (__float_as_uint(eh[j] - acc[i][j][r]) & ~31u)
                              | (unsigned)(nt * 4 + j);
          kq[j] = __uint_as_float(kb);
        }
        const float lo01 = fminf(kq[0], kq[1]), hi01 = fmaxf(kq[0], kq[1]);
        const float lo23 = fminf(kq[2], kq[3]), hi23 = fmaxf(kq[2], kq[3]);
        const float best = fminf(lo01, lo23);
        const float sec  = fminf(fmaxf(lo01, lo23), fminf(hi01, hi23));
        b2[s] = fminf(fmaxf(best, b1[s]), fminf(sec, b2[s]));
        b1[s] = fminf(best, b1[s]);
      }
    }
    bSrcT += 65536;   // next 128 codebook rows
  }
#undef KSTEP

  // ---- once per block: u64 butterfly top-2 merge (lane id in low bits), write cand
#pragma unroll
  for (int s = 0; s < 16; ++s) {
    u64 x1 = ((u64)__float_as_uint(b1[s]) << 32) | (unsigned)l15;
    u64 x2 = ((u64)__float_as_uint(b2[s]) << 32) | (unsigned)l15;
#pragma unroll
    for (int off = 1; off < 16; off <<= 1) {
      const u64 o1 = __shfl_xor(x1, off, 64);
      const u64 o2 = __shfl_xor(x2, off, 64);
      const u64 lo = umin64(x1, o1);
      const u64 hi = umax64(x1, o1);
      x1 = lo;
      x2 = umin64(hi, umin64(x2, o2));
    }
    if (l15 == 0) {
      const int i = s >> 2, r = s & 3;
      const int q = q0 + wq0 + i * 16 + quad * 4 + r;
      const unsigned kb1 = (unsigned)(x1 >> 32), kb2 = (unsigned)(x2 >> 32);
      const int n1 = split * 1024 + (int)((kb1 >> 2) & 7) * 128 + wn0
                     + 16 * (int)(kb1 & 3) + (int)(x1 & 15);
      const int n2 = split * 1024 + (int)((kb2 >> 2) & 7) * 128 + wn0
                     + 16 * (int)(kb2 & 3) + (int)(x2 & 15);
      cand[(size_t)q * 32 + split * 4 + wh * 2 + 0] = ((u64)kb1 << 32) | (unsigned)n1;
      cand[(size_t)q * 32 + split * 4 + wh * 2 + 1] = ((u64)kb2 << 32) | (unsigned)n2;
    }
  }
}

// ---------------- kernel 3: select + fp64 rescore (native z) + output ----------------
__global__ __launch_bounds__(256) void k_pick_out(const float* __restrict__ z,
                                                  const float* __restrict__ emb,
                                                  const u64* __restrict__ cand,
                                                  float* __restrict__ out) {
  __shared__ float zs[16][257];
  __shared__ float tile[16][257];
  const int t    = (int)threadIdx.x;
  const int lane = t & 63;
  const int wv   = t >> 6;
  const int sub  = lane >> 4;
  const int l15  = lane & 15;
  const int q0b  = (int)blockIdx.x * 16;
  const int b    = q0b >> 10, hw0 = q0b & 1023;
  const int q    = q0b + wv * 4 + sub;
  const int hwl  = wv * 4 + sub;

  // ---- phase 0: stage z slice (thread t = channel)
  {
    const float* zp = z + ((size_t)(b * CD + t)) * HW + hw0;
    const float4 a0 = *(const float4*)(zp + 0);
    const float4 a1 = *(const float4*)(zp + 4);
    const float4 a2 = *(const float4*)(zp + 8);
    const float4 a3 = *(const float4*)(zp + 12);
    zs[0][t] = a0.x;  zs[1][t] = a0.y;  zs[2][t] = a0.z;  zs[3][t] = a0.w;
    zs[4][t] = a1.x;  zs[5][t] = a1.y;  zs[6][t] = a1.z;  zs[7][t] = a1.w;
    zs[8][t] = a2.x;  zs[9][t] = a2.y;  zs[10][t] = a2.z; zs[11][t] = a2.w;
    zs[12][t] = a3.x; zs[13][t] = a3.y; zs[14][t] = a3.z; zs[15][t] = a3.w;
  }
  __syncthreads();

  // ---- phase 1: top-4-of-32 select (butterfly merge of sorted-2 lists)
  const u64* cp = cand + (size_t)q * 32 + l15 * 2;
  const u64 v0 = cp[0], v1 = cp[1];
  u64 s0 = umin64(v0, v1), s1 = umax64(v0, v1), s2 = ~0ull, s3 = ~0ull;
#pragma unroll
  for (int off = 1; off < 16; off <<= 1) {
    const u64 b0 = __shfl_xor(s0, off, 64);
    const u64 b1 = __shfl_xor(s1, off, 64);
    const u64 b2 = __shfl_xor(s2, off, 64);
    const u64 b3 = __shfl_xor(s3, off, 64);
    const u64 c0 = umin64(s0, b0);
    const u64 c1 = umin64(umin64(s1, b1), umax64(s0, b0));
    const u64 c2 = umin64(umin64(s2, b2),
                          umin64(umax64(s1, b0), umax64(s0, b1)));
    const u64 c3 = umin64(umin64(umin64(s3, b3), umax64(s2, b0)),
                          umin64(umax64(s0, b2), umax64(s1, b1)));
    s0 = c0; s1 = c1; s2 = c2; s3 = c3;
  }
  const u64 sel[4] = {s0, s1, s2, s3};

  // ---- phase 2: fp64 rescore, lane handles channels c = j*16 + l15
  float zq[16];
#pragma unroll
  for (int j = 0; j < 16; ++j) zq[j] = zs[hwl][j * 16 + l15];

  double bd = 1e300;
  int bi = 0x7fffffff;
  float keep[16];
#pragma unroll
  for (int j = 0; j < 16; ++j) keep[j] = 0.f;
#pragma unroll
  for (int c4 = 0; c4 < 4; ++c4) {
    const int idx = (int)(unsigned)(sel[c4] & 0xffffffffull);
    const float* er = emb + (size_t)idx * CD;
    float ev[16];
#pragma unroll
    for (int j = 0; j < 16; ++j) ev[j] = er[j * 16 + l15];
    double s = 0.0;
#pragma unroll
    for (int j = 0; j < 16; ++j) {
      const double d = (double)zq[j] - (double)ev[j];
      s += d * d;
    }
#pragma unroll
    for (int off = 1; off < 16; off <<= 1) s += __shfl_xor(s, off, 64);
    const bool better = (s < bd) || (s == bd && idx < bi);  // uniform in 16-lane group
    if (better) {
      bd = s; bi = idx;
#pragma unroll
      for (int j = 0; j < 16; ++j) keep[j] = ev[j];
    }
  }
  // ---- phase 3: winner row -> tile, transpose-store to out
#pragma unroll
  for (int j = 0; j < 16; ++j) tile[hwl][j * 16 + l15] = keep[j];
  __syncthreads();
  const int cluster = t >> 4;   // 0..15
  const int ll      = t & 15;
  float* obase = out + (size_t)b * CD * HW + hw0 + ll;
#pragma unroll
  for (int j = 0; j < 16; ++j) {
    const int c = 16 * j + cluster;
    obase[(size_t)c * HW] = tile[ll][c];
  }
}

extern "C" void kernel_launch(void* const* d_in, const int* in_sizes, int n_in,
                              void* d_out, int out_size, void* d_ws, size_t ws_size,
                              hipStream_t stream) {
  const float* z   = (const float*)d_in[0];
  const float* emb = (const float*)d_in[1];
  float* out = (float*)d_out;

  char* ws = (char*)d_ws;
  u16*   zTb  = (u16*)(ws + ZTB_OFF);
  u16*   embB = (u16*)(ws + EMBB_OFF);
  float* eH   = (float*)(ws + EH_OFF);
  u64*   cand = (u64*)(ws + CAND_OFF);

  k_prep<<<1280, 256, 0, stream>>>(z, emb, zTb, embB, eH);
  k_argmin<<<1024, 256, 0, stream>>>(zTb, embB, eH, cand);
  k_pick_out<<<1024, 256, 0, stream>>>(z, emb, cand, out);
}

// Round 2
// 173.288 us; speedup vs baseline: 1.8027x; 1.8027x over previous
//
#include <hip/hip_runtime.h>
#include <stdint.h>

#define NB   16
#define CD   256
#define HW   1024
#define NQ   16384
#define KCN  8192

typedef unsigned long long u64;
typedef unsigned short     u16;
using f32x4  = __attribute__((ext_vector_type(4))) float;
using bf16x8 = __attribute__((ext_vector_type(8))) __bf16;

// ---------------- workspace layout (~16.9 MB) ----------------
#define ZTB_OFF  0            // u16  [NQ][CD]    8 MB  (z transposed, bf16)
#define EMBB_OFF 8388608      // u16  [KCN][CD]   4 MB  (emb, bf16)
#define EH_OFF   12582912     // f32  [KCN]      32 KB  (||e||^2/2 + 1024)
#define CAND_OFF 12615680     // u64  [NQ][32]    4 MB  (8 splits x 2 halves x top-2)

static __device__ __forceinline__ void gl_lds16(const void* g, void* l) {
  __builtin_amdgcn_global_load_lds(
      (const __attribute__((address_space(1))) void*)g,
      (__attribute__((address_space(3))) void*)l, 16, 0, 0);
}

static __device__ __forceinline__ unsigned bf16r(float x) {  // RNE fp32->bf16 bits
  unsigned u = __float_as_uint(x);
  return (u + 0x7fffu + ((u >> 16) & 1u)) >> 16;
}

static __device__ __forceinline__ u64 umin64(u64 a, u64 b) { return a < b ? a : b; }
static __device__ __forceinline__ u64 umax64(u64 a, u64 b) { return a < b ? b : a; }

// ---------------- kernel 1: merged prep (unchanged) ----------------
__global__ __launch_bounds__(256) void k_prep(const float* __restrict__ z,
                                              const float* __restrict__ emb,
                                              u16* __restrict__ zTb,
                                              u16* __restrict__ embB,
                                              float* __restrict__ eH) {
  const int bx = (int)blockIdx.x;
  if (bx < 1024) {
    __shared__ float tile[64][65];
    const int b   = bx >> 6;
    const int hwT = (bx >> 2) & 15;
    const int cT  = bx & 3;
    const int tx  = threadIdx.x & 63;
    const int ty  = threadIdx.x >> 6;
    const float* src = z + (size_t)(b * CD + cT * 64) * HW + hwT * 64;
#pragma unroll
    for (int i = 0; i < 16; ++i) {
      const int c_l = ty + 4 * i;
      tile[c_l][tx] = src[(size_t)c_l * HW + tx];
    }
    __syncthreads();
    const size_t dbase = (size_t)(b * HW + hwT * 64) * CD + cT * 64;
#pragma unroll
    for (int i = 0; i < 16; ++i) {
      const int hw_l = ty + 4 * i;
      zTb[dbase + (size_t)hw_l * CD + tx] = (u16)bf16r(tile[tx][hw_l]);
    }
  } else {
    const int wave = (bx - 1024) * 4 + ((int)threadIdx.x >> 6);  // 0..1023
    const int lane = threadIdx.x & 63;
#pragma unroll
    for (int it = 0; it < 8; ++it) {
      const int row = wave * 8 + it;
      const float4 v = *(const float4*)(emb + (size_t)row * CD + lane * 4);
      uint2 pk;
      pk.x = bf16r(v.x) | (bf16r(v.y) << 16);
      pk.y = bf16r(v.z) | (bf16r(v.w) << 16);
      *(uint2*)(embB + (size_t)row * CD + lane * 4) = pk;
      float s = v.x * v.x + v.y * v.y + v.z * v.z + v.w * v.w;
#pragma unroll
      for (int off = 32; off; off >>= 1) s += __shfl_xor(s, off, 64);
      if (lane == 0) eH[row] = 0.5f * s + 1024.0f;
    }
  }
}

// ---------------- kernel 2: R11 — A-in-registers + 4-deep B ring + counted vmcnt ----
// R10 post-mortem: (256,4) reg cap 128 < ~150 live -> acc spilled to scratch
// (WRITE_SIZE 4->295MB). R9's real limit: vmcnt(0) drain at every __syncthreads.
// R11: wave owns 32 q-rows; A frags (16 x bf16x8 = 64 VGPR) loaded ONCE - no A
// staging, no A LDS. B: 4-slot LDS ring (4 x 16KB), stage 3 chunks ahead, waits
// counted (8/16, never 0 mid-loop), ONE s_barrier per 32-MFMA interval, setprio
// around MFMA. VMEM issue order pinned by memory-clobber asm (in-order vmcnt).
// Buckets: per split, n-half (j>>2) x top-2 -> same 32 cands/q; cand layout and
// k_pick_out unchanged. ~215 VGPR under (256,2) cap 256; LDS 64KB -> 2 blocks/CU.

#define WAITV(N) asm volatile("s_waitcnt vmcnt(" #N ")" ::: "memory")
#define MEMFENCE() asm volatile("" ::: "memory")

__global__ __launch_bounds__(256, 2) void k_argmin(const u16* __restrict__ zTb,
                                                   const u16* __restrict__ embB,
                                                   const float* __restrict__ eH,
                                                   u64* __restrict__ cand) {
  __shared__ __align__(16) u16 Bs[4][128 * 64];   // 16 KB per ring slot

  const int tid  = (int)threadIdx.x;
  const int w    = tid >> 6;
  const int lane = tid & 63;
  const int l15  = lane & 15, quad = lane >> 4;
  const int q0    = (int)(blockIdx.x >> 3) * 128;
  const int split = (int)(blockIdx.x & 7);

  // ---- A fragments: resident in registers for the whole kernel (64 VGPR)
  // Af[i][kc][ks][lane(quad,l15)] = A[q0+w*32+i*16+l15][kc*64+ks*32+quad*8 ..+7]
  bf16x8 Af[2][4][2];
  {
    const char* aB = (const char*)zTb
                   + ((size_t)(q0 + w * 32 + l15) * CD + quad * 8) * 2;
#pragma unroll
    for (int i = 0; i < 2; ++i)
#pragma unroll
      for (int kc = 0; kc < 4; ++kc)
#pragma unroll
        for (int ks = 0; ks < 2; ++ks)
          Af[i][kc][ks] = *(const bf16x8*)(aB + i * 8192 + kc * 128 + ks * 64);
  }
  MEMFENCE();   // pin: A loads issue before any staging DMA (in-order vmcnt math)

  // ---- B staging: thread writes LDS bytes [w*4096 + u*1024 + lane*16], u=0..3
  // -> row = w*32+u*8+(lane>>3), slot = lane&7; source granule = slot ^ (row&7)
  // (pre-swizzled global source, linear LDS dest: m173 pattern; R9-proven 0-conflict)
  const char* bS = (const char*)embB + (size_t)split * (1024 * 512)
                 + (size_t)(w * 32 + (lane >> 3)) * 512
                 + (size_t)(((lane & 7) ^ (lane >> 3)) * 16);
  const int ldsW = w * 4096 + lane * 16;

#define STAGE(RING, NT_, KC_)                                                  \
  do {                                                                         \
    const char* _s = bS + (NT_) * 65536 + (KC_) * 128;                         \
    char* _d = (char*)Bs[RING] + ldsW;                                         \
    gl_lds16(_s,         _d);                                                  \
    gl_lds16(_s + 4096,  _d + 1024);                                           \
    gl_lds16(_s + 8192,  _d + 2048);                                           \
    gl_lds16(_s + 12288, _d + 3072);                                           \
  } while (0)

  // frag-read byte offsets: B[n=j*16+l15][granule ks*4+quad] stored at
  // slot = (ks*4+quad) ^ (l15&7); ks flips bit2 of slot -> XOR 64 bytes
  const int bR0 = l15 * 128 + ((quad ^ (l15 & 7)) * 16);
  const int bR1 = bR0 ^ 64;

  f32x4 acc[2][8];
  float b1[8][2], b2[8][2];
  const float FMAX = __uint_as_float(0x7F7FFFFFu);
#pragma unroll
  for (int s = 0; s < 8; ++s) { b1[s][0] = b1[s][1] = FMAX; b2[s][0] = b2[s][1] = FMAX; }

  // ---- prologue: stage chunks 0,1,2 (ring = kc since c = nt*4+kc)
  STAGE(0, 0, 0); MEMFENCE();
  STAGE(1, 0, 1); MEMFENCE();
  STAGE(2, 0, 2); MEMFENCE();

#define MFMA_INT(RING, KC_)                                                    \
  do {                                                                         \
    const char* _b = (const char*)Bs[RING];                                    \
    _Pragma("unroll")                                                          \
    for (int ks = 0; ks < 2; ++ks) {                                           \
      bf16x8 bfr[8];                                                           \
      const int _o = ks ? bR1 : bR0;                                           \
      _Pragma("unroll")                                                        \
      for (int j = 0; j < 8; ++j)                                              \
        bfr[j] = *(const bf16x8*)(_b + j * 2048 + _o);                         \
      __builtin_amdgcn_s_setprio(1);                                           \
      _Pragma("unroll")                                                        \
      for (int i = 0; i < 2; ++i)                                              \
        _Pragma("unroll")                                                      \
        for (int j = 0; j < 8; ++j)                                            \
          acc[i][j] = __builtin_amdgcn_mfma_f32_16x16x32_bf16(                 \
              Af[i][KC_][ks], bfr[j], acc[i][j], 0, 0, 0);                     \
      __builtin_amdgcn_s_setprio(0);                                           \
    }                                                                          \
  } while (0)

#define EPILOGUE(NT_)                                                          \
  do {                                                                         \
    _Pragma("unroll")                                                          \
    for (int i = 0; i < 2; ++i)                                                \
      _Pragma("unroll")                                                        \
      for (int r = 0; r < 4; ++r) {                                            \
        const int s = i * 4 + r;                                               \
        float kq[8];                                                           \
        _Pragma("unroll")                                                      \
        for (int j = 0; j < 8; ++j)                                            \
          kq[j] = __uint_as_float(                                             \
              (__float_as_uint(eh[j] - acc[i][j][r]) & ~63u)                   \
              | (unsigned)((NT_) * 8 + j));                                    \
        _Pragma("unroll")                                                      \
        for (int h = 0; h < 2; ++h) {                                          \
          const float k0 = kq[4 * h], k1 = kq[4 * h + 1];                      \
          const float k2 = kq[4 * h + 2], k3 = kq[4 * h + 3];                  \
          const float lo01 = fminf(k0, k1), hi01 = fmaxf(k0, k1);              \
          const float lo23 = fminf(k2, k3), hi23 = fmaxf(k2, k3);              \
          const float best = fminf(lo01, lo23);                                \
          const float sec  = fminf(fmaxf(lo01, lo23), fminf(hi01, hi23));      \
          b2[s][h] = fminf(fmaxf(best, b1[s][h]), fminf(sec, b2[s][h]));       \
          b1[s][h] = fminf(best, b1[s][h]);                                    \
        }                                                                      \
      }                                                                        \
  } while (0)

  float eh[8];

  // ---- main loop nt = 0..6: waits 8,16,16,16; stage 3 chunks ahead
  for (int nt = 0; nt < 7; ++nt) {
    const int n0 = split * 1024 + nt * 128;
#pragma unroll
    for (int i = 0; i < 2; ++i)
#pragma unroll
      for (int j = 0; j < 8; ++j) acc[i][j] = f32x4{0.f, 0.f, 0.f, 0.f};

    // kc0: compute ring0, stage (nt,3)->ring3, load eh (order pinned)
    WAITV(8); __builtin_amdgcn_s_barrier(); MEMFENCE();
    STAGE(3, nt, 3); MEMFENCE();
#pragma unroll
    for (int j = 0; j < 8; ++j) eh[j] = eH[n0 + j * 16 + l15];
    MEMFENCE();
    MFMA_INT(0, 0);
    // kc1: compute ring1, stage (nt+1,0)->ring0
    WAITV(16); __builtin_amdgcn_s_barrier(); MEMFENCE();
    STAGE(0, nt + 1, 0); MEMFENCE();
    MFMA_INT(1, 1);
    // kc2: compute ring2, stage (nt+1,1)->ring1
    WAITV(16); __builtin_amdgcn_s_barrier(); MEMFENCE();
    STAGE(1, nt + 1, 1); MEMFENCE();
    MFMA_INT(2, 2);
    // kc3: compute ring3, stage (nt+1,2)->ring2
    WAITV(16); __builtin_amdgcn_s_barrier(); MEMFENCE();
    STAGE(2, nt + 1, 2); MEMFENCE();
    MFMA_INT(3, 3);

    EPILOGUE(nt);
  }

  // ---- peeled nt = 7: waits 8,16,12,8; only kc0 stages (chunk 31)
  {
    const int n0 = split * 1024 + 7 * 128;
#pragma unroll
    for (int i = 0; i < 2; ++i)
#pragma unroll
      for (int j = 0; j < 8; ++j) acc[i][j] = f32x4{0.f, 0.f, 0.f, 0.f};

    WAITV(8); __builtin_amdgcn_s_barrier(); MEMFENCE();
    STAGE(3, 7, 3); MEMFENCE();
#pragma unroll
    for (int j = 0; j < 8; ++j) eh[j] = eH[n0 + j * 16 + l15];
    MEMFENCE();
    MFMA_INT(0, 0);

    WAITV(16); __builtin_amdgcn_s_barrier(); MEMFENCE();
    MFMA_INT(1, 1);

    WAITV(12); __builtin_amdgcn_s_barrier(); MEMFENCE();
    MFMA_INT(2, 2);

    WAITV(8); __builtin_amdgcn_s_barrier(); MEMFENCE();
    MFMA_INT(3, 3);

    EPILOGUE(7);
  }
#undef STAGE
#undef MFMA_INT
#undef EPILOGUE

  // ---- per-wave: u64 butterfly top-2 merge over 16 lanes, write cand
#pragma unroll
  for (int s = 0; s < 8; ++s) {
#pragma unroll
    for (int h = 0; h < 2; ++h) {
      u64 x1 = ((u64)__float_as_uint(b1[s][h]) << 32) | (unsigned)l15;
      u64 x2 = ((u64)__float_as_uint(b2[s][h]) << 32) | (unsigned)l15;
#pragma unroll
      for (int off = 1; off < 16; off <<= 1) {
        const u64 o1 = __shfl_xor(x1, off, 64);
        const u64 o2 = __shfl_xor(x2, off, 64);
        const u64 lo = umin64(x1, o1);
        const u64 hi = umax64(x1, o1);
        x1 = lo;
        x2 = umin64(hi, umin64(x2, o2));
      }
      if (l15 == 0) {
        const int i = s >> 2, r = s & 3;
        const int q = q0 + w * 32 + i * 16 + quad * 4 + r;
        const unsigned kb1 = (unsigned)(x1 >> 32), kb2 = (unsigned)(x2 >> 32);
        const int n1 = split * 1024 + (int)((kb1 >> 3) & 7) * 128
                       + (int)(kb1 & 7) * 16 + (int)(x1 & 15);
        const int n2 = split * 1024 + (int)((kb2 >> 3) & 7) * 128
                       + (int)(kb2 & 7) * 16 + (int)(x2 & 15);
        cand[(size_t)q * 32 + split * 4 + h * 2 + 0] = ((u64)kb1 << 32) | (unsigned)n1;
        cand[(size_t)q * 32 + split * 4 + h * 2 + 1] = ((u64)kb2 << 32) | (unsigned)n2;
      }
    }
  }
}

// ---------------- kernel 3: select + fp64 rescore (native z) + output (unchanged) ----
__global__ __launch_bounds__(256) void k_pick_out(const float* __restrict__ z,
                                                  const float* __restrict__ emb,
                                                  const u64* __restrict__ cand,
                                                  float* __restrict__ out) {
  __shared__ float zs[16][257];
  __shared__ float tile[16][257];
  const int t    = (int)threadIdx.x;
  const int lane = t & 63;
  const int wv   = t >> 6;
  const int sub  = lane >> 4;
  const int l15  = lane & 15;
  const int q0b  = (int)blockIdx.x * 16;
  const int b    = q0b >> 10, hw0 = q0b & 1023;
  const int q    = q0b + wv * 4 + sub;
  const int hwl  = wv * 4 + sub;

  // ---- phase 0: stage z slice (thread t = channel)
  {
    const float* zp = z + ((size_t)(b * CD + t)) * HW + hw0;
    const float4 a0 = *(const float4*)(zp + 0);
    const float4 a1 = *(const float4*)(zp + 4);
    const float4 a2 = *(const float4*)(zp + 8);
    const float4 a3 = *(const float4*)(zp + 12);
    zs[0][t] = a0.x;  zs[1][t] = a0.y;  zs[2][t] = a0.z;  zs[3][t] = a0.w;
    zs[4][t] = a1.x;  zs[5][t] = a1.y;  zs[6][t] = a1.z;  zs[7][t] = a1.w;
    zs[8][t] = a2.x;  zs[9][t] = a2.y;  zs[10][t] = a2.z; zs[11][t] = a2.w;
    zs[12][t] = a3.x; zs[13][t] = a3.y; zs[14][t] = a3.z; zs[15][t] = a3.w;
  }
  __syncthreads();

  // ---- phase 1: top-4-of-32 select (butterfly merge of sorted-2 lists)
  const u64* cp = cand + (size_t)q * 32 + l15 * 2;
  const u64 v0 = cp[0], v1 = cp[1];
  u64 s0 = umin64(v0, v1), s1 = umax64(v0, v1), s2 = ~0ull, s3 = ~0ull;
#pragma unroll
  for (int off = 1; off < 16; off <<= 1) {
    const u64 b0 = __shfl_xor(s0, off, 64);
    const u64 b1 = __shfl_xor(s1, off, 64);
    const u64 b2 = __shfl_xor(s2, off, 64);
    const u64 b3 = __shfl_xor(s3, off, 64);
    const u64 c0 = umin64(s0, b0);
    const u64 c1 = umin64(umin64(s1, b1), umax64(s0, b0));
    const u64 c2 = umin64(umin64(s2, b2),
                          umin64(umax64(s1, b0), umax64(s0, b1)));
    const u64 c3 = umin64(umin64(umin64(s3, b3), umax64(s2, b0)),
                          umin64(umax64(s0, b2), umax64(s1, b1)));
    s0 = c0; s1 = c1; s2 = c2; s3 = c3;
  }
  const u64 sel[4] = {s0, s1, s2, s3};

  // ---- phase 2: fp64 rescore, lane handles channels c = j*16 + l15
  float zq[16];
#pragma unroll
  for (int j = 0; j < 16; ++j) zq[j] = zs[hwl][j * 16 + l15];

  double bd = 1e300;
  int bi = 0x7fffffff;
  float keep[16];
#pragma unroll
  for (int j = 0; j < 16; ++j) keep[j] = 0.f;
#pragma unroll
  for (int c4 = 0; c4 < 4; ++c4) {
    const int idx = (int)(unsigned)(sel[c4] & 0xffffffffull);
    const float* er = emb + (size_t)idx * CD;
    float ev[16];
#pragma unroll
    for (int j = 0; j < 16; ++j) ev[j] = er[j * 16 + l15];
    double s = 0.0;
#pragma unroll
    for (int j = 0; j < 16; ++j) {
      const double d = (double)zq[j] - (double)ev[j];
      s += d * d;
    }
#pragma unroll
    for (int off = 1; off < 16; off <<= 1) s += __shfl_xor(s, off, 64);
    const bool better = (s < bd) || (s == bd && idx < bi);  // uniform in 16-lane group
    if (better) {
      bd = s; bi = idx;
#pragma unroll
      for (int j = 0; j < 16; ++j) keep[j] = ev[j];
    }
  }
  // ---- phase 3: winner row -> tile, transpose-store to out
#pragma unroll
  for (int j = 0; j < 16; ++j) tile[hwl][j * 16 + l15] = keep[j];
  __syncthreads();
  const int cluster = t >> 4;   // 0..15
  const int ll      = t & 15;
  float* obase = out + (size_t)b * CD * HW + hw0 + ll;
#pragma unroll
  for (int j = 0; j < 16; ++j) {
    const int c = 16 * j + cluster;
    obase[(size_t)c * HW] = tile[ll][c];
  }
}

extern "C" void kernel_launch(void* const* d_in, const int* in_sizes, int n_in,
                              void* d_out, int out_size, void* d_ws, size_t ws_size,
                              hipStream_t stream) {
  const float* z   = (const float*)d_in[0];
  const float* emb = (const float*)d_in[1];
  float* out = (float*)d_out;

  char* ws = (char*)d_ws;
  u16*   zTb  = (u16*)(ws + ZTB_OFF);
  u16*   embB = (u16*)(ws + EMBB_OFF);
  float* eH   = (float*)(ws + EH_OFF);
  u64*   cand = (u64*)(ws + CAND_OFF);

  k_prep<<<1280, 256, 0, stream>>>(z, emb, zTb, embB, eH);
  k_argmin<<<1024, 256, 0, stream>>>(zTb, embB, eH, cand);
  k_pick_out<<<1024, 256, 0, stream>>>(z, emb, cand, out);
}